// Round 14
// baseline (2494.762 us; speedup 1.0000x reference)
//
#include <hip/hip_runtime.h>

// ---------------------------------------------------------------------------
// 2-layer LSTM (B=256,T=1024,in=64,H=128) + FC(128->32), bf16 MFMA.
// Layer-pipelined: 128 blocks = 64 L0 + 64 L1; handoff via out0 + agent-scope
// flags (release per chunk; L1 lags 2 chunks). CH=8, R=4.
// R14: register-accX (R13) + next-chunk accX GEMM SLICED INTO THE STEPS
// (tt=2..5, after gate chains, before EW) so independent MFMAs fill the
// MFMA pipe while EW's trans chain + h-write drain. L1 x-frags go through a
// single xfr register buffer with >=1-step load->use slack (no same-step
// vmcnt stall - R12's bug fixed). EW reordered: i,f,g -> c,tanh(c) while
// o-chain+slices issue -> o last. FC weights chunk-scoped (VGPR relief).
// ---------------------------------------------------------------------------

static constexpr int B   = 256;
static constexpr int T   = 1024;
static constexpr int H   = 128;
static constexpr int O   = 32;
static constexpr int R   = 4;          // batch rows per block
static constexpr int NBL = B / R;      // 64 blocks per layer
static constexpr int CH  = 8;          // steps per chunk
static constexpr int NCH = T / CH;     // 128 chunks

// LDS layout (units: shorts)
static constexpr int HROW = H + 8;                  // 136
static constexpr int HB   = 0;                      // Hbuf [2][16][HROW]
static constexpr int HH   = HB + 2 * 16 * HROW;     // Hhist[2][16][HROW]
static constexpr int XROW = 72;                     // L0 x row stride
static constexpr int XB   = HH + 2 * 16 * HROW;     // Xbuf [2][32][XROW]
static constexpr int LDSN = XB + 2 * 32 * XROW;     // 13312 shorts = 26.6 KB

typedef __attribute__((ext_vector_type(8))) short  short8;
typedef __attribute__((ext_vector_type(4))) float  f32x4;

#define LOG2E 1.4426950408889634f

#if __has_builtin(__builtin_amdgcn_exp2f)
#define EXP2(x) __builtin_amdgcn_exp2f(x)
#else
#define EXP2(x) __expf((x) * 0.69314718056f)
#endif
#if __has_builtin(__builtin_amdgcn_rcpf)
#define RCP(x) __builtin_amdgcn_rcpf(x)
#else
#define RCP(x) (1.0f / (x))
#endif

__device__ __forceinline__ unsigned short f2bf(float f) {
  unsigned int u = __builtin_bit_cast(unsigned int, f);
  u += 0x7fffu + ((u >> 16) & 1u);        // round-to-nearest-even
  return (unsigned short)(u >> 16);
}

__device__ __forceinline__ float sigm(float x) {
  return RCP(1.0f + EXP2(-LOG2E * x));
}
__device__ __forceinline__ float tanh_f(float x) {
  return 1.0f - 2.0f * RCP(1.0f + EXP2(2.0f * LOG2E * x));
}

__device__ __forceinline__ short8 cvt8(const float* s) {
  float4 a = *(const float4*)s;
  float4 b = *(const float4*)(s + 4);
  short8 v;
  v[0] = (short)f2bf(a.x); v[1] = (short)f2bf(a.y);
  v[2] = (short)f2bf(a.z); v[3] = (short)f2bf(a.w);
  v[4] = (short)f2bf(b.x); v[5] = (short)f2bf(b.y);
  v[6] = (short)f2bf(b.z); v[7] = (short)f2bf(b.w);
  return v;
}

// LDS-only barrier: wait own ds ops, then s_barrier. Global ops float.
__device__ __forceinline__ void block_sync_lds() {
  __builtin_amdgcn_sched_barrier(0);
  asm volatile("s_waitcnt lgkmcnt(0)" ::: "memory");
  __builtin_amdgcn_s_barrier();
  __builtin_amdgcn_sched_barrier(0);
}

// ---------------------------------------------------------------------------
// One layer's full-T scan for R=4 batch rows. 8 waves; wave w owns gate cols
// [w*16,w*16+16) of i,f,g,o. Lane owns batch row lhi (gate-tile row lhi*4,
// acc reg 0). accX/X tiles: M-row m = (bb<<2)|(ts&3), tile q = ts>>2.
// ---------------------------------------------------------------------------
template <int KIN, bool IN_BF16, bool WRITE_HOUT, bool FUSE_FC, bool PROD, bool CONS>
__device__ __forceinline__ void scan_body(
    unsigned short* __restrict__ S,          // LDS, LDSN shorts
    const void* __restrict__ in_,            // [B,T,KIN] f32 (L0) / bf16 (L1)
    const float* __restrict__ h0,
    const float* __restrict__ c0,
    const float* __restrict__ Wih,           // [4H,KIN]
    const float* __restrict__ Whh,           // [4H,H]
    const float* __restrict__ bih,
    const float* __restrict__ bhh,
    unsigned short* __restrict__ hout,       // bf16 [B,T,H] (L0 only)
    float* __restrict__ hN,
    float* __restrict__ cN,
    const float* __restrict__ Wfc,           // [32,128] (L1 only)
    const float* __restrict__ bfc,
    float* __restrict__ fco,                 // [B,T,32]
    int* __restrict__ flag, const int bbase)
{
  constexpr int KCX = KIN / 32;              // 2 (L0) or 4 (L1)
  constexpr int KCH = H / 32;                // 4

  const int tid  = threadIdx.x;
  const int w    = tid >> 6;
  const int l    = tid & 63;
  const int l15  = l & 15;
  const int lhi  = l >> 4;
  const int jcol = w * 16 + l15;

  // ---- persistent weight fragments ----
  short8 wfh[4][KCH], wfx[4][KCX];
  float  bias4[4];
#pragma unroll
  for (int gb = 0; gb < 4; ++gb) {
    const int gc = gb * H + jcol;
#pragma unroll
    for (int kc = 0; kc < KCX; ++kc)
      wfx[gb][kc] = cvt8(Wih + (size_t)gc * KIN + kc * 32 + lhi * 8);
#pragma unroll
    for (int kc = 0; kc < KCH; ++kc)
      wfh[gb][kc] = cvt8(Whh + (size_t)gc * H + kc * 32 + lhi * 8);
    bias4[gb] = bih[gc] + bhh[gc];
  }

  float cst   = c0[(size_t)(bbase + lhi) * H + jcol];
  float hlast = 0.f;

  const float*          inf = (const float*)in_;
  const unsigned short* inb = (const unsigned short*)in_;

  // ---- L0 staging coords (Xbuf tile row m of tile q = x[b+(m>>2)][q*4+(m&3)])
  const int srow = tid >> 4;                 // 0..31 (q = srow>>4, m = srow&15)
  const int scol = (tid & 15) * 4;
  const float* xs0 = inf +
      ((size_t)(bbase + ((srow & 15) >> 2)) * T + ((srow >> 4) * 4 + (srow & 3))) * KIN + scol;

  // ---- L1 direct A-frag source: lane covers (bb=l15>>2, ts=l15&3) ----
  const unsigned short* xg1 =
      inb + ((size_t)(bbase + (l15 >> 2)) * T + (l15 & 3)) * KIN + lhi * 8;

  unsigned short* hp = nullptr;
  if constexpr (WRITE_HOUT)
    hp = hout + (size_t)(bbase + lhi) * T * H + jcol;

  // ---- zero Hbuf ----
  for (int i = tid; i < 2 * 16 * HROW / 2; i += 512)
    ((unsigned int*)S)[i] = 0u;

  if constexpr (CONS) {
    if (tid == 0) {
      while (__hip_atomic_load(flag, __ATOMIC_ACQUIRE, __HIP_MEMORY_SCOPE_AGENT) < 2)
        __builtin_amdgcn_s_sleep(4);
    }
  }
  __syncthreads();   // covers zeroing + acquire

  // ---- prologue: h0 -> Hbuf[0]; stage chunk 0 (L0: Xbuf[0]) ----
  S[HB + (lhi * 4) * HROW + jcol] = f2bf(h0[(size_t)(bbase + lhi) * H + jcol]);
  if constexpr (!IN_BF16) {
    float4 v = *(const float4*)xs0;
    uint2 p;
    p.x = (unsigned int)f2bf(v.x) | ((unsigned int)f2bf(v.y) << 16);
    p.y = (unsigned int)f2bf(v.z) | ((unsigned int)f2bf(v.w) << 16);
    *(uint2*)&S[XB + srow * XROW + scol] = p;
  }
  __syncthreads();

  // ---- prologue accX GEMM for chunk 0 -> axc2 registers ----
  f32x4 axc2[4][2];
  short8 xfr[KCX];                            // L1 x A-frag buffer (1 tile)
#pragma unroll
  for (int q = 0; q < 2; ++q) {
    short8 afx[KCX];
#pragma unroll
    for (int kc = 0; kc < KCX; ++kc) {
      if constexpr (IN_BF16)
        afx[kc] = *(const short8*)(xg1 + (size_t)(q * 4) * KIN + kc * 32);
      else
        afx[kc] = *(const short8*)&S[XB + (q * 16 + l15) * XROW + kc * 32 + lhi * 8];
    }
#pragma unroll
    for (int gb = 0; gb < 4; ++gb) {
      f32x4 a = {bias4[gb], bias4[gb], bias4[gb], bias4[gb]};
#pragma unroll
      for (int kc = 0; kc < KCX; ++kc)
        a = __builtin_amdgcn_mfma_f32_16x16x32_bf16(afx[kc], wfx[gb][kc], a, 0, 0, 0);
      axc2[gb][q] = a;
    }
  }

  for (int k = 0; k < NCH; ++k) {
    if constexpr (CONS) {
      if (k > 0) {
        const int want = (k + 2 > NCH) ? NCH : (k + 2);
        if (tid == 0) {
          while (__hip_atomic_load(flag, __ATOMIC_ACQUIRE, __HIP_MEMORY_SCOPE_AGENT) < want)
            __builtin_amdgcn_s_sleep(4);
        }
        __syncthreads();
      }
    }

    const bool hasN = (k + 1 < NCH);
    f32x4 axn[4][2];
    float4 pf;

#pragma unroll
    for (int tt = 0; tt < CH; ++tt) {
      const int cur = tt & 1, nxt = cur ^ 1;

      // stage chunk k+1: L0 global->reg @tt0, reg->LDS @tt1 (1-step slack);
      // L1: xfr <- q0 of chunk k+1 @tt0 (used @tt2/3)
      if constexpr (!IN_BF16) {
        if (tt == 0 && hasN) pf = *(const float4*)(xs0 + (size_t)(k + 1) * CH * KIN);
        if (tt == 1 && hasN) {
          uint2 p;
          p.x = (unsigned int)f2bf(pf.x) | ((unsigned int)f2bf(pf.y) << 16);
          p.y = (unsigned int)f2bf(pf.z) | ((unsigned int)f2bf(pf.w) << 16);
          *(uint2*)&S[XB + (((k + 1) & 1) * 32 + srow) * XROW + scol] = p;
        }
      } else {
        if (tt == 0 && hasN) {
#pragma unroll
          for (int kc = 0; kc < KCX; ++kc)
            xfr[kc] = *(const short8*)(xg1 + (size_t)((k + 1) * CH) * KIN + kc * 32);
        }
      }

      // h(t-1) fragments
      short8 afh[KCH];
#pragma unroll
      for (int kc = 0; kc < KCH; ++kc)
        afh[kc] = *(const short8*)&S[HB + (cur * 16 + l15) * HROW + kc * 32 + lhi * 8];

      // gates = axc2[.][tt] + h @ Whh^T  (4 chains of 4)
      f32x4 acc[4];
#pragma unroll
      for (int gb = 0; gb < 4; ++gb) {
        const float ax = axc2[gb][tt >> 2][tt & 3];
        f32x4 a = {ax, ax, ax, ax};
#pragma unroll
        for (int kc = 0; kc < KCH; ++kc)
          a = __builtin_amdgcn_mfma_f32_16x16x32_bf16(afh[kc], wfh[gb][kc], a, 0, 0, 0);
        acc[gb] = a;
      }

      // ---- accX slices for chunk k+1: independent MFMAs that fill the
      // pipe while EW's dependent chain drains (2 gate-chains per step) ----
      if (hasN && tt >= 2 && tt <= 5) {
        const int q  = (tt - 2) >> 1;          // 0,0,1,1
        const int g0 = ((tt - 2) & 1) * 2;     // 0,2,0,2
        short8 afx[KCX];
#pragma unroll
        for (int kc = 0; kc < KCX; ++kc) {
          if constexpr (IN_BF16)
            afx[kc] = xfr[kc];
          else
            afx[kc] = *(const short8*)&S[XB + (((k + 1) & 1) * 32 + q * 16 + l15) * XROW +
                                         kc * 32 + lhi * 8];
        }
#pragma unroll
        for (int gg = 0; gg < 2; ++gg) {
          const int gb = g0 + gg;
          f32x4 a = {bias4[gb], bias4[gb], bias4[gb], bias4[gb]};
#pragma unroll
          for (int kc = 0; kc < KCX; ++kc)
            a = __builtin_amdgcn_mfma_f32_16x16x32_bf16(afx[kc], wfx[gb][kc], a, 0, 0, 0);
          axn[gb][q] = a;
        }
      }
      // L1: after q0's last use, refill xfr with q1 (used @tt4/5, 1-step slack)
      if constexpr (IN_BF16) {
        if (tt == 3 && hasN) {
#pragma unroll
          for (int kc = 0; kc < KCX; ++kc)
            xfr[kc] = *(const short8*)(xg1 + (size_t)((k + 1) * CH + 4) * KIN + kc * 32);
        }
      }

      // ---- EW: i,f,g first; c,tanh(c) while o-chain/slices drain; o last --
      {
        float i_ = sigm(acc[0][0]);
        float f_ = sigm(acc[1][0]);
        float g_ = tanh_f(acc[2][0]);
        float c_ = f_ * cst + i_ * g_;
        cst = c_;
        float tc = tanh_f(c_);
        float o_ = sigm(acc[3][0]);
        float hn = o_ * tc;
        hlast = hn;
        unsigned short hb = f2bf(hn);
        S[HB + (nxt * 16 + lhi * 4) * HROW + jcol] = hb;
        if constexpr (FUSE_FC)
          S[HH + ((lhi >> 1) * 16 + (lhi & 1) * 8 + tt) * HROW + jcol] = hb;
        if constexpr (WRITE_HOUT) { hp[0] = hb; hp += H; }
      }

      block_sync_lds();
    }

    // ---- chunk-batched FC (2 tiles of 2 rows x 8 ts from Hhist; waves 0-3)
    if constexpr (FUSE_FC) {
      if (w < 4) {
        short8 bfr[4];
        const int oc = (w & 1) * 16 + l15;
#pragma unroll
        for (int kc = 0; kc < 4; ++kc)
          bfr[kc] = cvt8(Wfc + (size_t)oc * H + kc * 32 + lhi * 8);
        const float fcb_ = bfc[oc];
        const int q = w >> 1;
        short8 a4[4];
#pragma unroll
        for (int kc = 0; kc < 4; ++kc)
          a4[kc] = *(const short8*)&S[HH + (q * 16 + l15) * HROW + kc * 32 + lhi * 8];
        f32x4 fs = {fcb_, fcb_, fcb_, fcb_};
#pragma unroll
        for (int kc = 0; kc < 4; ++kc)
          fs = __builtin_amdgcn_mfma_f32_16x16x32_bf16(a4[kc], bfr[kc], fs, 0, 0, 0);
        const int brow = bbase + q * 2 + (lhi >> 1);
        const int tb   = k * CH + (lhi & 1) * 4;
#pragma unroll
        for (int r = 0; r < 4; ++r)
          fco[((size_t)brow * T + tb + r) * O + (w & 1) * 16 + l15] = fs[r];
      }
    }

    // rotate accX pipeline
    if (hasN) {
#pragma unroll
      for (int gb = 0; gb < 4; ++gb) {
        axc2[gb][0] = axn[gb][0];
        axc2[gb][1] = axn[gb][1];
      }
    }

    if constexpr (PROD) {
      __builtin_amdgcn_sched_barrier(0);
      asm volatile("s_waitcnt vmcnt(0)" ::: "memory");
      __builtin_amdgcn_s_barrier();
      if (tid == 0)
        __hip_atomic_store(flag, k + 1, __ATOMIC_RELEASE, __HIP_MEMORY_SCOPE_AGENT);
    }
  }

  // ---- tails ----
  hN[(size_t)(bbase + lhi) * H + jcol] = hlast;
  cN[(size_t)(bbase + lhi) * H + jcol] = cst;
}

// ---------------------------------------------------------------------------
__global__ __launch_bounds__(512, 2) void lstm_fused(
    const float* __restrict__ x,
    const float* __restrict__ h0, const float* __restrict__ c0,
    const float* __restrict__ Wih0, const float* __restrict__ Whh0,
    const float* __restrict__ bih0, const float* __restrict__ bhh0,
    const float* __restrict__ Wih1, const float* __restrict__ Whh1,
    const float* __restrict__ bih1, const float* __restrict__ bhh1,
    const float* __restrict__ fcw, const float* __restrict__ fcb,
    unsigned short* __restrict__ out0,
    float* __restrict__ out, float* __restrict__ hN, float* __restrict__ cN,
    int* __restrict__ flags)
{
  __shared__ __align__(16) unsigned short S[LDSN];   // 26.6 KB
  const int bid = blockIdx.x;
  if (bid < NBL) {
    // L0 producer
    scan_body<64, false, true, false, true, false>(
        S, x, h0, c0, Wih0, Whh0, bih0, bhh0,
        out0, hN, cN, nullptr, nullptr, nullptr,
        flags + bid, bid * R);
  } else {
    // L1 consumer + chunk-batched FC
    const int rb = bid - NBL;
    scan_body<128, true, false, true, false, true>(
        S, out0, h0 + B * H, c0 + B * H, Wih1, Whh1, bih1, bhh1,
        nullptr, hN + B * H, cN + B * H, fcw, fcb, out,
        flags + rb, rb * R);
  }
}

// ---------------------------------------------------------------------------
extern "C" void kernel_launch(void* const* d_in, const int* in_sizes, int n_in,
                              void* d_out, int out_size, void* d_ws, size_t ws_size,
                              hipStream_t stream) {
  (void)in_sizes; (void)n_in; (void)out_size; (void)ws_size;

  const float* x    = (const float*)d_in[0];
  const float* h0   = (const float*)d_in[1];
  const float* c0   = (const float*)d_in[2];
  const float* Wih0 = (const float*)d_in[3];
  const float* Whh0 = (const float*)d_in[4];
  const float* bih0 = (const float*)d_in[5];
  const float* bhh0 = (const float*)d_in[6];
  const float* Wih1 = (const float*)d_in[7];
  const float* Whh1 = (const float*)d_in[8];
  const float* bih1 = (const float*)d_in[9];
  const float* bhh1 = (const float*)d_in[10];
  const float* fcw  = (const float*)d_in[11];
  const float* fcb  = (const float*)d_in[12];

  int*            flags = (int*)d_ws;                             // 64 ints
  unsigned short* out0  = (unsigned short*)((char*)d_ws + 1024);  // bf16 [B,T,H]

  float* out = (float*)d_out;                                     // [B,T,32]
  float* hN  = out + (size_t)B * T * O;                           // [2,B,H]
  float* cN  = hN + (size_t)2 * B * H;                            // [2,B,H]

  hipMemsetAsync(d_ws, 0, 1024, stream);   // reset pipeline flags every launch
  lstm_fused<<<2 * NBL, 512, 0, stream>>>(
      x, h0, c0, Wih0, Whh0, bih0, bhh0, Wih1, Whh1, bih1, bhh1,
      fcw, fcb, out0, out, hN, cN, flags);
}

// Round 15
// 717.649 us; speedup vs baseline: 3.4763x; 3.4763x over previous
//
#include <hip/hip_runtime.h>

// ---------------------------------------------------------------------------
// 2-layer LSTM (B=256,T=1024,in=64,H=128) + FC(128->32), bf16 MFMA.
// Layer-pipelined: 128 blocks = 64 L0 + 64 L1; L1 lags L0 by 2 chunks (CH=8),
// handoff via global out0 + agent-scope release/acquire flags.
// R15 = R10 (714us, best known) + two zero-state micro-changes:
//  - #pragma unroll on the 8-step tt loop: all LDS offsets (AX+tt*520, Hbuf
//    cur/nxt, Hhist row) become compile-time immediates; kills ~100-200
//    VALU-cy/step of address math + loop overhead. No new live registers
//    (R13/R14 lesson: chunk-lifetime register state spills next to weights).
//  - EW reorder: i,f,g -> c -> tanh(c) -> o last.
// Everything else is R10 verbatim.
// ---------------------------------------------------------------------------

static constexpr int B   = 256;
static constexpr int T   = 1024;
static constexpr int H   = 128;
static constexpr int O   = 32;
static constexpr int R   = 4;          // batch rows per block
static constexpr int NBL = B / R;      // 64 blocks per layer
static constexpr int CH  = 8;          // steps per chunk
static constexpr int NCH = T / CH;     // 128 chunks

// LDS layout (units: shorts)
static constexpr int HROW = H + 8;                 // 136
static constexpr int HB   = 0;                     // Hbuf [2][16][HROW]
static constexpr int HH   = HB + 2 * 16 * HROW;    // Hhist[2][16][HROW]
static constexpr int XB   = HH + 2 * 16 * HROW;    // Xbuf [2][16][XROW<=HROW]
static constexpr int AX   = XB + 2 * 16 * HROW;    // accXL[4][AXB]
static constexpr int AXB  = 8 * 520 + 8;           // 4168 shorts per batch row
static constexpr int LDSN = AX + 4 * AXB;          // 29728 shorts = 59456 B

typedef __attribute__((ext_vector_type(8))) short  short8;
typedef __attribute__((ext_vector_type(4))) float  f32x4;

#define LOG2E 1.4426950408889634f

#if __has_builtin(__builtin_amdgcn_exp2f)
#define EXP2(x) __builtin_amdgcn_exp2f(x)
#else
#define EXP2(x) __expf((x) * 0.69314718056f)
#endif
#if __has_builtin(__builtin_amdgcn_rcpf)
#define RCP(x) __builtin_amdgcn_rcpf(x)
#else
#define RCP(x) (1.0f / (x))
#endif

__device__ __forceinline__ unsigned short f2bf(float f) {
  unsigned int u = __builtin_bit_cast(unsigned int, f);
  u += 0x7fffu + ((u >> 16) & 1u);        // round-to-nearest-even
  return (unsigned short)(u >> 16);
}
__device__ __forceinline__ float bf2f(unsigned short s) {
  return __builtin_bit_cast(float, (unsigned int)s << 16);
}

__device__ __forceinline__ float sigm(float x) {
  return RCP(1.0f + EXP2(-LOG2E * x));
}
__device__ __forceinline__ float tanh_f(float x) {
  return 1.0f - 2.0f * RCP(1.0f + EXP2(2.0f * LOG2E * x));
}

// LDS-only barrier: wait own ds ops, then s_barrier. Global ops float.
__device__ __forceinline__ void block_sync_lds() {
  __builtin_amdgcn_sched_barrier(0);
  asm volatile("s_waitcnt lgkmcnt(0)" ::: "memory");
  __builtin_amdgcn_s_barrier();
  __builtin_amdgcn_sched_barrier(0);
}

// ---------------------------------------------------------------------------
// One layer's full-T scan for R=4 batch rows. 8 waves; wave w owns gate cols
// [w*16,w*16+16) of each gate block (i,f,g,o). Lane owns batch row lhi
// (tile row lhi*4, acc reg 0).
// ---------------------------------------------------------------------------
template <int KIN, bool IN_BF16, bool WRITE_HOUT, bool FUSE_FC, bool PROD, bool CONS>
__device__ __forceinline__ void scan_body(
    unsigned short* __restrict__ S,          // LDS, LDSN shorts
    const void* __restrict__ in_,            // [B,T,KIN] f32 (L0) / bf16 (L1)
    const float* __restrict__ h0,
    const float* __restrict__ c0,
    const float* __restrict__ Wih,           // [4H,KIN]
    const float* __restrict__ Whh,           // [4H,H]
    const float* __restrict__ bih,
    const float* __restrict__ bhh,
    unsigned short* __restrict__ hout,       // bf16 [B,T,H] (L0 only)
    float* __restrict__ hN,
    float* __restrict__ cN,
    const float* __restrict__ Wfc,           // [32,128] (L1 only)
    const float* __restrict__ bfc,
    float* __restrict__ fco,                 // [B,T,32]
    int* __restrict__ flag, const int bbase)
{
  constexpr int KCX  = KIN / 32;             // 2 or 4
  constexpr int KCH  = H / 32;               // 4
  constexpr int XROW = KIN + 8;              // 72 or 136

  const int tid  = threadIdx.x;
  const int w    = tid >> 6;
  const int l    = tid & 63;
  const int l15  = l & 15;
  const int lhi  = l >> 4;
  const int jcol = w * 16 + l15;

  // ---- weight fragments ----
  short8 wfx[4][KCX], wfh[4][KCH];
  float  bias4[4];
#pragma unroll
  for (int gb = 0; gb < 4; ++gb) {
    const int gc = gb * H + jcol;
    const float* wi = Wih + (size_t)gc * KIN;
    const float* wh = Whh + (size_t)gc * H;
#pragma unroll
    for (int kc = 0; kc < KCX; ++kc) {
      const float* s = wi + kc * 32 + lhi * 8;
      float4 a = *(const float4*)s;
      float4 b = *(const float4*)(s + 4);
      short8 v;
      v[0] = (short)f2bf(a.x); v[1] = (short)f2bf(a.y);
      v[2] = (short)f2bf(a.z); v[3] = (short)f2bf(a.w);
      v[4] = (short)f2bf(b.x); v[5] = (short)f2bf(b.y);
      v[6] = (short)f2bf(b.z); v[7] = (short)f2bf(b.w);
      wfx[gb][kc] = v;
    }
#pragma unroll
    for (int kc = 0; kc < KCH; ++kc) {
      const float* s = wh + kc * 32 + lhi * 8;
      float4 a = *(const float4*)s;
      float4 b = *(const float4*)(s + 4);
      short8 v;
      v[0] = (short)f2bf(a.x); v[1] = (short)f2bf(a.y);
      v[2] = (short)f2bf(a.z); v[3] = (short)f2bf(a.w);
      v[4] = (short)f2bf(b.x); v[5] = (short)f2bf(b.y);
      v[6] = (short)f2bf(b.z); v[7] = (short)f2bf(b.w);
      wfh[gb][kc] = v;
    }
    bias4[gb] = bih[gc] + bhh[gc];
  }

  // ---- FC weight fragments (used by waves 0-3; loads always valid) ----
  short8 bfr[4];
  float fcbias = 0.f;
  if constexpr (FUSE_FC) {
    const int oc = (w & 1) * 16 + l15;
#pragma unroll
    for (int kc = 0; kc < 4; ++kc) {
      const float* s = Wfc + (size_t)oc * H + kc * 32 + lhi * 8;
      float4 a = *(const float4*)s;
      float4 b = *(const float4*)(s + 4);
      short8 v;
      v[0] = (short)f2bf(a.x); v[1] = (short)f2bf(a.y);
      v[2] = (short)f2bf(a.z); v[3] = (short)f2bf(a.w);
      v[4] = (short)f2bf(b.x); v[5] = (short)f2bf(b.y);
      v[6] = (short)f2bf(b.z); v[7] = (short)f2bf(b.w);
      bfr[kc] = v;
    }
    fcbias = bfc[oc];
  }

  float cst   = c0[(size_t)(bbase + lhi) * H + jcol];
  float hlast = 0.f;

  const float*          inf = (const float*)in_;
  const unsigned short* inb = (const unsigned short*)in_;

  // ---- X staging lane mapping: (q, row) with b = q*2 + row>>3, ts = row&7 ----
  const int sq  = tid >> 8;                  // GEMM tile 0..1
  const int srw = (tid >> 4) & 15;           // M row 0..15
  const int sb  = bbase + sq * 2 + (srw >> 3);
  const int sts = srw & 7;
  const float*          xsf = inf + ((size_t)sb * T + sts) * KIN + (tid & 15) * 4;
  const unsigned short* xsb = inb + ((size_t)sb * T + sts) * KIN + (tid & 15) * 8;
  const int xdst = XB + (sq * 16 + srw) * XROW +
                   (IN_BF16 ? (tid & 15) * 8 : (tid & 15) * 4);

  unsigned short* hp = nullptr;
  if constexpr (WRITE_HOUT)
    hp = hout + (size_t)(bbase + lhi) * T * H + jcol;

  // ---- zero Hbuf (both buffers) once; garbage M rows stay 0 ----
  for (int i = tid; i < 2 * 16 * HROW / 2; i += 512)
    ((unsigned int*)S)[i] = 0u;
  __syncthreads();

  // ---- consumer: wait for chunks 0,1 before touching in_ ----
  if constexpr (CONS) {
    if (tid == 0) {
      while (__hip_atomic_load(flag, __ATOMIC_ACQUIRE, __HIP_MEMORY_SCOPE_AGENT) < 2)
        __builtin_amdgcn_s_sleep(4);
    }
    __syncthreads();
  }

  // ---- prologue: stage Xbuf chunk 0; h0 -> Hbuf[0] ----
  if constexpr (IN_BF16) {
    uint4 v = *(const uint4*)xsb;
    *(uint4*)&S[xdst] = v;
  } else {
    float4 v = *(const float4*)xsf;
    uint2 p;
    p.x = (unsigned int)f2bf(v.x) | ((unsigned int)f2bf(v.y) << 16);
    p.y = (unsigned int)f2bf(v.z) | ((unsigned int)f2bf(v.w) << 16);
    *(uint2*)&S[xdst] = p;
  }
  S[HB + (lhi * 4) * HROW + jcol] = f2bf(h0[(size_t)(bbase + lhi) * H + jcol]);
  __syncthreads();

  int cur = 0;
  for (int k = 0; k < NCH; ++k) {
    if constexpr (CONS) {
      if (k > 0) {
        const int want = (k + 2 > NCH) ? NCH : (k + 2);
        if (tid == 0) {
          while (__hip_atomic_load(flag, __ATOMIC_ACQUIRE, __HIP_MEMORY_SCOPE_AGENT) < want)
            __builtin_amdgcn_s_sleep(4);
        }
        __syncthreads();
      }
    }

    // ---- accX chunk GEMM: 2 packed GEMMs (2 batch rows x 8 ts in M=16) ----
#pragma unroll
    for (int q = 0; q < 2; ++q) {
      short8 afx[KCX];
#pragma unroll
      for (int kc = 0; kc < KCX; ++kc)
        afx[kc] = *(const short8*)&S[XB + (q * 16 + l15) * XROW + kc * 32 + lhi * 8];
#pragma unroll
      for (int gb = 0; gb < 4; ++gb) {
        f32x4 a = {bias4[gb], bias4[gb], bias4[gb], bias4[gb]};
#pragma unroll
        for (int kc = 0; kc < KCX; ++kc)
          a = __builtin_amdgcn_mfma_f32_16x16x32_bf16(afx[kc], wfx[gb][kc], a, 0, 0, 0);
        const int bb = q * 2 + (lhi >> 1);
#pragma unroll
        for (int r = 0; r < 4; ++r) {
          const int ts = (lhi & 1) * 4 + r;
          S[AX + bb * AXB + ts * 520 + gb * 128 + jcol] = f2bf(a[r]);
        }
      }
    }
    // producer==consumer wave for accXL (col ownership matches) -> no barrier

    // ---- 8 recurrence steps (UNROLLED: LDS offsets become immediates) ----
    float4 sF; uint4 sB;                     // staging regs for chunk k+1
#pragma unroll
    for (int tt = 0; tt < CH; ++tt) {
      if (k + 1 < NCH) {
        if (tt == 0) {
          if constexpr (IN_BF16) sB = *(const uint4*)(xsb + (size_t)(k + 1) * CH * KIN);
          else                   sF = *(const float4*)(xsf + (size_t)(k + 1) * CH * KIN);
        } else if (tt == 1) {    // all waves past GEMM reads (step-0 barrier)
          if constexpr (IN_BF16) {
            *(uint4*)&S[xdst] = sB;
          } else {
            uint2 p;
            p.x = (unsigned int)f2bf(sF.x) | ((unsigned int)f2bf(sF.y) << 16);
            p.y = (unsigned int)f2bf(sF.z) | ((unsigned int)f2bf(sF.w) << 16);
            *(uint2*)&S[xdst] = p;
          }
        }
      }

      // accX for this step (own batch row = lhi)
      float ax[4];
#pragma unroll
      for (int gb = 0; gb < 4; ++gb)
        ax[gb] = bf2f(S[AX + lhi * AXB + tt * 520 + gb * 128 + jcol]);

      // h(t-1) fragments
      short8 afh[KCH];
#pragma unroll
      for (int kc = 0; kc < KCH; ++kc)
        afh[kc] = *(const short8*)&S[HB + (cur * 16 + l15) * HROW + kc * 32 + lhi * 8];

      // gates = accX + h @ Whh^T
      f32x4 acc[4];
#pragma unroll
      for (int gb = 0; gb < 4; ++gb) {
        f32x4 a = {ax[gb], ax[gb], ax[gb], ax[gb]};
#pragma unroll
        for (int kc = 0; kc < KCH; ++kc)
          a = __builtin_amdgcn_mfma_f32_16x16x32_bf16(afh[kc], wfh[gb][kc], a, 0, 0, 0);
        acc[gb] = a;
      }

      const int nxt = cur ^ 1;
      // elementwise (1 row per lane); o-gate computed after tanh(c)
      {
        float i_ = sigm(acc[0][0]);
        float f_ = sigm(acc[1][0]);
        float g_ = tanh_f(acc[2][0]);
        float c_ = f_ * cst + i_ * g_;
        cst = c_;
        float tc = tanh_f(c_);
        float o_ = sigm(acc[3][0]);
        float hn = o_ * tc;
        hlast = hn;
        unsigned short hb = f2bf(hn);
        S[HB + (nxt * 16 + lhi * 4) * HROW + jcol] = hb;
        if constexpr (FUSE_FC)
          S[HH + ((lhi >> 1) * 16 + (lhi & 1) * 8 + tt) * HROW + jcol] = hb;
        if constexpr (WRITE_HOUT) { hp[0] = hb; }
      }
      if constexpr (WRITE_HOUT) hp += H;

      block_sync_lds();
      cur = nxt;
    }

    // ---- batched FC for this chunk (h(t) for t in chunk; waves 0-3) ----
    if constexpr (FUSE_FC) {
      if (w < 4) {
        const int q = w >> 1;
        short8 a4[4];
#pragma unroll
        for (int kc = 0; kc < 4; ++kc)
          a4[kc] = *(const short8*)&S[HH + (q * 16 + l15) * HROW + kc * 32 + lhi * 8];
        f32x4 fs = {fcbias, fcbias, fcbias, fcbias};
#pragma unroll
        for (int kc = 0; kc < 4; ++kc)
          fs = __builtin_amdgcn_mfma_f32_16x16x32_bf16(a4[kc], bfr[kc], fs, 0, 0, 0);
        const int brow = bbase + q * 2 + (lhi >> 1);
        const int tb   = k * CH + (lhi & 1) * 4;
#pragma unroll
        for (int r = 0; r < 4; ++r)
          fco[((size_t)brow * T + tb + r) * O + (w & 1) * 16 + l15] = fs[r];
      }
    }

    if constexpr (PROD) {
      __builtin_amdgcn_sched_barrier(0);
      asm volatile("s_waitcnt vmcnt(0)" ::: "memory");
      __builtin_amdgcn_s_barrier();
      if (tid == 0)
        __hip_atomic_store(flag, k + 1, __ATOMIC_RELEASE, __HIP_MEMORY_SCOPE_AGENT);
    }
  }

  // ---- tails ----
  hN[(size_t)(bbase + lhi) * H + jcol] = hlast;
  cN[(size_t)(bbase + lhi) * H + jcol] = cst;
}

// ---------------------------------------------------------------------------
__global__ __launch_bounds__(512, 2) void lstm_fused(
    const float* __restrict__ x,
    const float* __restrict__ h0, const float* __restrict__ c0,
    const float* __restrict__ Wih0, const float* __restrict__ Whh0,
    const float* __restrict__ bih0, const float* __restrict__ bhh0,
    const float* __restrict__ Wih1, const float* __restrict__ Whh1,
    const float* __restrict__ bih1, const float* __restrict__ bhh1,
    const float* __restrict__ fcw, const float* __restrict__ fcb,
    unsigned short* __restrict__ out0,
    float* __restrict__ out, float* __restrict__ hN, float* __restrict__ cN,
    int* __restrict__ flags)
{
  __shared__ __align__(16) unsigned short S[LDSN];   // 59.5 KB
  const int bid = blockIdx.x;
  if (bid < NBL) {
    // L0 producer
    scan_body<64, false, true, false, true, false>(
        S, x, h0, c0, Wih0, Whh0, bih0, bhh0,
        out0, hN, cN, nullptr, nullptr, nullptr,
        flags + bid, bid * R);
  } else {
    // L1 consumer + chunk-batched FC
    const int rb = bid - NBL;
    scan_body<128, true, false, true, false, true>(
        S, out0, h0 + B * H, c0 + B * H, Wih1, Whh1, bih1, bhh1,
        nullptr, hN + B * H, cN + B * H, fcw, fcb, out,
        flags + rb, rb * R);
  }
}

// ---------------------------------------------------------------------------
extern "C" void kernel_launch(void* const* d_in, const int* in_sizes, int n_in,
                              void* d_out, int out_size, void* d_ws, size_t ws_size,
                              hipStream_t stream) {
  (void)in_sizes; (void)n_in; (void)out_size; (void)ws_size;

  const float* x    = (const float*)d_in[0];
  const float* h0   = (const float*)d_in[1];
  const float* c0   = (const float*)d_in[2];
  const float* Wih0 = (const float*)d_in[3];
  const float* Whh0 = (const float*)d_in[4];
  const float* bih0 = (const float*)d_in[5];
  const float* bhh0 = (const float*)d_in[6];
  const float* Wih1 = (const float*)d_in[7];
  const float* Whh1 = (const float*)d_in[8];
  const float* bih1 = (const float*)d_in[9];
  const float* bhh1 = (const float*)d_in[10];
  const float* fcw  = (const float*)d_in[11];
  const float* fcb  = (const float*)d_in[12];

  int*            flags = (int*)d_ws;                             // 64 ints
  unsigned short* out0  = (unsigned short*)((char*)d_ws + 1024);  // bf16 [B,T,H]

  float* out = (float*)d_out;                                     // [B,T,32]
  float* hN  = out + (size_t)B * T * O;                           // [2,B,H]
  float* cN  = hN + (size_t)2 * B * H;                            // [2,B,H]

  hipMemsetAsync(d_ws, 0, 1024, stream);   // reset pipeline flags every launch
  lstm_fused<<<2 * NBL, 512, 0, stream>>>(
      x, h0, c0, Wih0, Whh0, bih0, bhh0, Wih1, Whh1, bih1, bhh1,
      fcw, fcb, out0, out, hN, cN, flags);
}